// Round 4
// baseline (384.135 us; speedup 1.0000x reference)
//
#include <hip/hip_runtime.h>
#include <stdint.h>

// Shapes from reference
#define Bn   4
#define Cn   720
#define Hn   128
#define Wn   128
#define Pn   9
#define OFFn 80           // Cn / Pn
#define HWn  16384        // Hn * Wn  (= 2^14)
#define TPB  1024         // 16 waves/block
#define PRE_TPB 256
#define NBLK 256          // persistent blocks, 1 per CU (128 KB LDS)

// ---------------------------------------------------------------------------
// Kernel 1 (unchanged from round 3): precompute per-(b,p,pos) gather record
// {base=y0*Wn+x0 (bit-cast), dy, dx, pad} = 16 B. 9.44 MB in d_ws.
// ---------------------------------------------------------------------------
__global__ __launch_bounds__(PRE_TPB) void dcn_precompute_kernel(
    const float* __restrict__ loc,
    float4* __restrict__ ws)
{
    const int idx = blockIdx.x * PRE_TPB + threadIdx.x;   // over Bn*Pn*HWn
    const int pos = idx & (HWn - 1);
    const int bp  = idx >> 14;          // b * Pn + p
    const int b   = bp / Pn;
    const int p   = bp - b * Pn;

    const float yq = loc[((size_t)b * (2 * Pn) + 2 * p)     * HWn + pos];
    const float xq = loc[((size_t)b * (2 * Pn) + 2 * p + 1) * HWn + pos];

    const float y0f = floorf(yq);
    const float x0f = floorf(xq);
    const float dy  = yq - y0f;
    const float dx  = xq - x0f;

    int y0 = min(max((int)y0f, 0), Hn - 2);
    int x0 = min(max((int)x0f, 0), Wn - 2);
    const int base = y0 * Wn + x0;

    ws[idx] = make_float4(__int_as_float(base), dy, dx, 0.f);
}

// ---------------------------------------------------------------------------
// Async 16B global->LDS (gfx950 global_load_lds_dwordx4).
// Per-lane GLOBAL address; wave-uniform LDS base; HW writes lane i at
// ldsbase + i*16 (guide §5: linear dest, no per-lane scatter).
// ---------------------------------------------------------------------------
__device__ __forceinline__ void async_ld16(const void* g, void* l)
{
    __builtin_amdgcn_global_load_lds(
        (__attribute__((address_space(1))) void*)(g),
        (__attribute__((address_space(3))) void*)(l),
        16, 0, 0);
}

// Stage one 64 KB plane: 64 segments of 1024 B (64 lanes x 16 B).
// Wave w issues segments 4w..4w+3. Fully async; caller syncs.
__device__ __forceinline__ void stage_plane_async(
    const float* __restrict__ src, float* dstLDS, int tid)
{
    const int wave = tid >> 6;
    const int lane = tid & 63;
    #pragma unroll
    for (int k = 0; k < 4; ++k) {
        const int seg = wave * 4 + k;
        async_ld16(src + seg * 256 + lane * 4,   // per-lane global addr
                   dstLDS + seg * 256);          // wave-uniform LDS base
    }
}

// ---------------------------------------------------------------------------
// Kernel 2: persistent double-buffered pipeline. 256 blocks (1/CU), each
// owns 11-12 CONSECUTIVE (b,c) planes (stays inside one (b,p) group most of
// its life -> ws slice stays L2-hot). Per channel:
//   issue async stage of NEXT plane into buf[cur^1]   (HBM read, off the
//   gather from buf[cur] (ws L2 read, 2x ds_read2,      critical path)
//     7 FMA, float4 store)
//   __syncthreads()  -- its vmcnt(0)-drain is the prefetch wait; the
//                       prefetch had the whole gather phase to land.
// Removes the serial stage->barrier->gather structure of rounds 0-3, which
// left every pipe <50% busy (latency-bound: HBM 34%, LDS 25%, VALU 11%).
// ---------------------------------------------------------------------------
__global__ __launch_bounds__(TPB) void dcn_bilinear_pipe_kernel(
    const float* __restrict__ x,
    const float4* __restrict__ ws,
    const float* __restrict__ bias,
    float* __restrict__ out)
{
    __shared__ float buf[2][HWn];    // 128 KB double buffer

    // 2880 = 256*11 + 64: blocks 0..63 take 12 channels, 64..255 take 11.
    const int g     = blockIdx.x;
    const int extra = (g < 64) ? g : 64;
    const int start = g * 11 + extra;
    const int cnt   = 11 + (g < 64 ? 1 : 0);
    const int tid   = threadIdx.x;

    // Prologue: stage first plane.
    stage_plane_async(x + (size_t)start * HWn, buf[0], tid);
    __syncthreads();

    int cur = 0;
    for (int i = 0; i < cnt; ++i) {
        const int bc = start + i;
        const int b  = bc / Cn;
        const int c  = bc - b * Cn;
        const int p  = c / OFFn;

        // Prefetch next plane (async; completes under the gather below).
        if (i + 1 < cnt)
            stage_plane_async(x + (size_t)(bc + 1) * HWn, buf[cur ^ 1], tid);

        const float bv = bias[c];
        const float4* wsp = ws + (size_t)(b * Pn + p) * HWn;
        float4* ob4 = (float4*)(out + (size_t)bc * HWn);
        const float* spl = buf[cur];

        #pragma unroll 2
        for (int k = 0; k < HWn / 4 / TPB; ++k) {       // 4 iterations
            const int q = tid + k * TPB;
            float4 r;
            float* rs = &r.x;
            #pragma unroll
            for (int j = 0; j < 4; ++j) {
                const float4 w = wsp[4 * q + j];
                const int   base = __float_as_int(w.x);
                const float dy   = w.y;
                const float dx   = w.z;

                const float* r0 = spl + base;
                const float v00 = r0[0];
                const float v01 = r0[1];
                const float v10 = r0[Wn];
                const float v11 = r0[Wn + 1];

                const float omdy = 1.f - dy;
                const float omdx = 1.f - dx;
                rs[j] = omdy * (omdx * v00 + dx * v01)
                      + dy   * (omdx * v10 + dx * v11) + bv;
            }
            ob4[q] = r;
        }

        // Drains vmcnt(0): (a) prefetch writes into buf[cur^1] are complete,
        // (b) all waves done reading buf[cur] before next iter overwrites it.
        __syncthreads();
        cur ^= 1;
    }
}

extern "C" void kernel_launch(void* const* d_in, const int* in_sizes, int n_in,
                              void* d_out, int out_size, void* d_ws, size_t ws_size,
                              hipStream_t stream)
{
    const float* x    = (const float*)d_in[0];
    const float* loc  = (const float*)d_in[1];
    const float* bias = (const float*)d_in[2];
    float* out        = (float*)d_out;
    float4* ws        = (float4*)d_ws;     // needs Bn*Pn*HWn*16 = 9.44 MB

    dim3 pgrid(Bn * Pn * HWn / PRE_TPB);   // 2304 blocks
    dcn_precompute_kernel<<<pgrid, PRE_TPB, 0, stream>>>(loc, ws);

    dim3 grid(NBLK);                       // 256 persistent blocks, 1/CU
    dcn_bilinear_pipe_kernel<<<grid, TPB, 0, stream>>>(x, ws, bias, out);
}

// Round 5
// 334.585 us; speedup vs baseline: 1.1481x; 1.1481x over previous
//
#include <hip/hip_runtime.h>
#include <stdint.h>

// Shapes from reference
#define Bn    4
#define Cn    720
#define Hn    128
#define Wn    128
#define Pn    9
#define OFFn  80          // Cn / Pn
#define HWn   16384       // Hn * Wn (= 2^14)
#define TPB   1024        // 16 waves/block
#define NBLK  256         // persistent, 1 block/CU (128 KB LDS)
#define PLANES   (Bn * Cn)      // 2880 (b,c) planes; group id = plane/80 == b*Pn+p
#define PER_XCD  (PLANES / 8)   // 360 planes per XCD
#define NSLOT    (NBLK / 8)     // 32 blocks per XCD

// ---------------------------------------------------------------------------
// Async 16B global->LDS (global_load_lds_dwordx4): per-lane GLOBAL address,
// wave-uniform LDS base, HW writes lane i at ldsbase + i*16 (linear dest).
// ---------------------------------------------------------------------------
__device__ __forceinline__ void async_ld16(const void* g, void* l)
{
    __builtin_amdgcn_global_load_lds(
        (__attribute__((address_space(1))) void*)(g),
        (__attribute__((address_space(3))) void*)(l),
        16, 0, 0);
}

// Stage one 64 KB plane: 64 segments of 1024 B (64 lanes x 16 B); wave w
// issues segments 4w..4w+3. Fully async; caller's __syncthreads() drains.
__device__ __forceinline__ void stage_plane_async(
    const float* __restrict__ src, float* dstLDS, int tid)
{
    const int wave = tid >> 6;
    const int lane = tid & 63;
    #pragma unroll
    for (int k = 0; k < 4; ++k) {
        const int seg = wave * 4 + k;
        async_ld16(src + seg * 256 + lane * 4, dstLDS + seg * 256);
    }
}

// ---------------------------------------------------------------------------
// Persistent double-buffered pipeline, round-4 structure with two fixes:
//
// 1) NO ws table / NO per-channel loc reads: each thread's 16 gather records
//    {base, dy, dx} are computed ONCE per (b,p) group and held in 48 VGPRs
//    across the ~80-channel group (<=2 group crossings per block). Round 4's
//    FETCH explosion (459 MB vs 193 MB of x) was the per-channel ws re-read
//    thrashing L2; this removes that traffic class entirely.
//
// 2) XCD-aware plane assignment: hardware maps blockIdx round-robin to XCDs,
//    so block g = (xcd = g&7, slot = g>>3) takes a contiguous 11-12-plane
//    span of XCD xcd's 360-plane region. Slice-sharing blocks land on the
//    SAME XCD -> ~5 live loc slices (0.6 MB) per 4 MB L2.
//
// Per channel: issue async prefetch of next plane into buf[cur^1], gather
// current channel from buf[cur] via register records (2x ds_read2_b32 +
// 7 FMA per position), float4 store, __syncthreads() (its vmcnt(0) drain is
// the prefetch wait - the prefetch had the whole gather phase to land).
// ---------------------------------------------------------------------------
__global__ __launch_bounds__(TPB) void dcn_persist_kernel(
    const float* __restrict__ x,
    const float* __restrict__ loc,
    const float* __restrict__ bias,
    float* __restrict__ out)
{
    __shared__ float buf[2][HWn];    // 128 KB double buffer

    const int g    = blockIdx.x;
    const int xcd  = g & 7;          // hw: consecutive blocks round-robin XCDs
    const int slot = g >> 3;         // 0..31 within XCD
    const int begin = xcd * PER_XCD + (slot * PER_XCD) / NSLOT;
    const int end   = xcd * PER_XCD + ((slot + 1) * PER_XCD) / NSLOT;
    const int tid   = threadIdx.x;

    // Per-thread gather records for this group's 16 positions (register-held;
    // all indexing below is compile-time via full unroll).
    int   rbase[4][4];
    float rdy[4][4];
    float rdx[4][4];

    // Prologue: stage first plane.
    stage_plane_async(x + (size_t)begin * HWn, buf[0], tid);
    __syncthreads();

    int cur = 0;
    int prev_gid = -1;
    for (int bc = begin; bc < end; ++bc) {
        // Prefetch next plane (async; completes under the gather below).
        if (bc + 1 < end)
            stage_plane_async(x + (size_t)(bc + 1) * HWn, buf[cur ^ 1], tid);

        // Recompute records on group entry (~1-2x per block lifetime).
        // loc y-plane for group gid lives at plane index 2*gid (= b*2P + 2p).
        const int gid = bc / OFFn;
        if (gid != prev_gid) {
            prev_gid = gid;
            const float4* ly4 = (const float4*)(loc + (size_t)(2 * gid) * HWn);
            const float4* lx4 = ly4 + HWn / 4;
            #pragma unroll
            for (int k = 0; k < 4; ++k) {
                const int q = tid + k * TPB;
                const float4 yv = ly4[q];
                const float4 xv = lx4[q];
                #pragma unroll
                for (int j = 0; j < 4; ++j) {
                    const float yq = (&yv.x)[j];
                    const float xq = (&xv.x)[j];
                    const float y0f = floorf(yq);
                    const float x0f = floorf(xq);
                    rdy[k][j] = yq - y0f;
                    rdx[k][j] = xq - x0f;
                    // location = uniform[0,127): strictly in-bounds; clamp is
                    // defensive only (bounds the LDS address).
                    const int y0 = min(max((int)y0f, 0), Hn - 2);
                    const int x0 = min(max((int)x0f, 0), Wn - 2);
                    rbase[k][j] = y0 * Wn + x0;
                }
            }
        }

        const int   c  = bc % Cn;
        const float bv = bias[c];
        float4* ob4 = (float4*)(out + (size_t)bc * HWn);
        const float* spl = buf[cur];

        // Gather: 4 float4 chunks = 16 positions per thread, records in regs.
        #pragma unroll
        for (int k = 0; k < 4; ++k) {
            const int q = tid + k * TPB;
            float4 r;
            #pragma unroll
            for (int j = 0; j < 4; ++j) {
                const float* r0 = spl + rbase[k][j];
                const float v00 = r0[0];
                const float v01 = r0[1];
                const float v10 = r0[Wn];
                const float v11 = r0[Wn + 1];
                const float dy = rdy[k][j];
                const float dx = rdx[k][j];
                const float omdy = 1.f - dy;
                const float omdx = 1.f - dx;
                (&r.x)[j] = omdy * (omdx * v00 + dx * v01)
                          + dy   * (omdx * v10 + dx * v11) + bv;
            }
            ob4[q] = r;
        }

        // Drains vmcnt(0): (a) prefetch into buf[cur^1] complete,
        // (b) all waves done with buf[cur] before it is overwritten.
        __syncthreads();
        cur ^= 1;
    }
}

extern "C" void kernel_launch(void* const* d_in, const int* in_sizes, int n_in,
                              void* d_out, int out_size, void* d_ws, size_t ws_size,
                              hipStream_t stream)
{
    const float* x    = (const float*)d_in[0];
    const float* loc  = (const float*)d_in[1];
    const float* bias = (const float*)d_in[2];
    float* out        = (float*)d_out;

    dim3 grid(NBLK);   // 256 persistent blocks, 1 per CU
    dcn_persist_kernel<<<grid, TPB, 0, stream>>>(x, loc, bias, out);
}